// Round 12
// baseline (287.262 us; speedup 1.0000x reference)
//
#include <hip/hip_runtime.h>
#include <hip/hip_bf16.h>

#define DI __device__ __forceinline__

typedef float f32x4 __attribute__((ext_vector_type(4)));
typedef short s16x8 __attribute__((ext_vector_type(8)));

constexpr int N_NODES = 50000;
constexpr int N_EDGES = 400000;
constexpr int G       = 64;
constexpr int C       = 32;
constexpr float BN_EPS = 1e-5f;

// ---------------- workspace layout (bytes) ----------------
constexpr size_t OFF_WH    = 0;                                   // [960][128] bf16 (Wl,Wr,We)
constexpr size_t OFF_SCALE = 245760;                              // [128] f32
constexpr size_t OFF_SHIFT = OFF_SCALE + 512;                     // [128] f32
constexpr size_t OFF_Y     = OFF_SHIFT + 512;                     // [N][640] bf16 (xl|xr, PAIRED)
constexpr size_t OFF_ALPHA = OFF_Y + (size_t)N_NODES * 640 * 2;   // [E][10] f32 (exp(alpha))
constexpr size_t OFF_DENOM = OFF_ALPHA + (size_t)N_EDGES * 10 * 4;// [N][10] f32
constexpr size_t OFF_ACC   = OFF_DENOM + (size_t)N_NODES * 10 * 4;// [N][32] f32
constexpr size_t OFF_POOL  = OFF_ACC + (size_t)N_NODES * 32 * 4;  // [64][32] f32
constexpr size_t OFF_CNT   = OFF_POOL + (size_t)G * C * 4;        // [64] f32

// y PAIRED layout: u32[n*320 + headg*16 + s] holds bf16 cols (headg*32+s, headg*32+16+s),
// headg 0..9 = xl heads, 10..19 = xr heads.

DI float bf2f(unsigned short u) {
    unsigned int x = ((unsigned int)u) << 16;
    float f; __builtin_memcpy(&f, &x, 4); return f;
}
DI unsigned short f2bf(float f) {
    unsigned int x; __builtin_memcpy(&x, &f, 4);
    x += 0x7FFFu + ((x >> 16) & 1u);
    return (unsigned short)(x >> 16);
}
DI float lo16(unsigned int u) {
    unsigned int x = u << 16; float f; __builtin_memcpy(&f, &x, 4); return f;
}
DI float hi16(unsigned int u) {
    unsigned int x = u & 0xffff0000u; float f; __builtin_memcpy(&f, &x, 4); return f;
}
DI unsigned int cvtpk(float a, float b) {  // v_cvt_pk_bf16_f32: lo=a, hi=b
    unsigned int r;
    asm("v_cvt_pk_bf16_f32 %0, %1, %2" : "=v"(r) : "v"(a), "v"(b));
    return r;
}
// XOR swizzle inside a 256B row (A tile: row stride 256B)
DI int swzA(int row, int kb) { return row * 256 + (kb ^ ((row & 7) << 4)); }

// raw barrier: drain LDS only, leave global prefetches in flight
DI void bar_sync() {
    __builtin_amdgcn_sched_barrier(0);
    asm volatile("s_waitcnt lgkmcnt(0)" ::: "memory");
    __builtin_amdgcn_s_barrier();
    __builtin_amdgcn_sched_barrier(0);
}

// ---------------- init ----------------
__global__ void k_init(const float* __restrict__ Wl, const float* __restrict__ Wr,
                       const float* __restrict__ We, const float* __restrict__ gamma,
                       const float* __restrict__ beta, const float* __restrict__ mean,
                       const float* __restrict__ var,
                       unsigned short* __restrict__ Wh, float* __restrict__ scale,
                       float* __restrict__ shift, float* __restrict__ denom,
                       float* __restrict__ accC, float* __restrict__ pooled,
                       float* __restrict__ cnt)
{
    int idx0 = blockIdx.x * blockDim.x + threadIdx.x;
    int stride = gridDim.x * blockDim.x;
    for (int i = idx0; i < 960 * 128; i += stride) {
        float v;
        if (i < 320 * 128)      v = Wl[i];
        else if (i < 640 * 128) v = Wr[i - 320 * 128];
        else                    v = We[i - 640 * 128];
        Wh[i] = f2bf(v);
    }
    for (int i = idx0; i < 128; i += stride) {
        float sc = gamma[i] * rsqrtf(var[i] + BN_EPS);
        scale[i] = sc;
        shift[i] = beta[i] - mean[i] * sc;
    }
    for (int i = idx0; i < N_NODES * 10; i += stride) denom[i] = 0.f;
    for (int i = idx0; i < N_NODES * 32; i += stride) accC[i] = 0.f;
    for (int i = idx0; i < G * C; i += stride) pooled[i] = 0.f;
    for (int i = idx0; i < G; i += stride) cnt[i] = 0.f;
}

// ---------------- node GEMM (Round-6-bench version: 4-chunk restage) --------
// B-chunk LDS layout: slot (col,k16') at byte col*64+k16'*16 holds global
// k-frag k16 = k16' ^ ((col>>1)&3). Writes linear; reads 2-way max.
__global__ __launch_bounds__(512)
void k_node_gemm(const float* __restrict__ x, const unsigned short* __restrict__ Wh,
                 const float* __restrict__ scale, const float* __restrict__ shift,
                 const float* __restrict__ bl, const float* __restrict__ br,
                 unsigned short* __restrict__ y)
{
    __shared__ unsigned char smem[36864];
    unsigned char* sA = smem;             // [64][256B] swizzled
    unsigned char* sB = smem + 16384;     // B chunk, 20KB
    const int tid = threadIdx.x;
    const int n0 = blockIdx.x * 64;
    const int ch = blockIdx.y;            // 0: Wl half, 1: Wr half
    const int wrow0 = ch * 320;

    // stage A (x with BN fused), fp32 -> bf16
#pragma unroll
    for (int it = 0; it < 4; ++it) {
        int c = tid + it * 512;           // 0..2047
        int row = c >> 5, q = c & 31;
        int n = n0 + row;
        f32x4 v = (f32x4){0.f, 0.f, 0.f, 0.f};
        if (n < N_NODES)
            v = __builtin_nontemporal_load(
                reinterpret_cast<const f32x4*>(x + (size_t)n * 128 + q * 4));
        float x0 = v[0] * scale[q * 4 + 0] + shift[q * 4 + 0];
        float x1 = v[1] * scale[q * 4 + 1] + shift[q * 4 + 1];
        float x2 = v[2] * scale[q * 4 + 2] + shift[q * 4 + 2];
        float x3 = v[3] * scale[q * 4 + 3] + shift[q * 4 + 3];
        uint2 pk = make_uint2(cvtpk(x0, x1), cvtpk(x2, x3));
        *reinterpret_cast<uint2*>(sA + swzA(row, q * 8)) = pk;
    }

    const int w = tid >> 6, l = tid & 63;
    const int rw = (w & 3) * 16;
    const int cq = (w >> 2) * 160;
    const int l15 = l & 15, l4 = l >> 4;

    f32x4 acc[10];
#pragma unroll
    for (int f = 0; f < 10; ++f) acc[f] = (f32x4){0.f, 0.f, 0.f, 0.f};

    for (int kq = 0; kq < 4; ++kq) {
        __syncthreads();                  // A ready (kq=0) / prev MFMA done (kq>0)
#pragma unroll
        for (int it = 0; it < 3; ++it) {
            int id = tid + it * 512;      // 0..1535, valid < 1280
            if (id < 1280) {
                int col = id >> 2;
                int k16 = (id & 3) ^ ((col >> 1) & 3);
                uint4 v = *reinterpret_cast<const uint4*>(
                    Wh + (size_t)(wrow0 + col) * 128 + kq * 32 + k16 * 8);
                *reinterpret_cast<uint4*>(sB + id * 16) = v;
            }
        }
        __syncthreads();
        s16x8 a = *reinterpret_cast<const s16x8*>(sA + swzA(rw + l15, kq * 64 + l4 * 16));
#pragma unroll
        for (int f = 0; f < 10; ++f) {
            int col = cq + f * 16 + l15;
            s16x8 b = *reinterpret_cast<const s16x8*>(
                sB + col * 64 + ((l4 ^ ((col >> 1) & 3)) << 4));
            acc[f] = __builtin_amdgcn_mfma_f32_16x16x32_bf16(a, b, acc[f], 0, 0, 0);
        }
    }

    const float* bias = ch ? br : bl;
    unsigned int* y32 = reinterpret_cast<unsigned int*>(y);
#pragma unroll
    for (int fp = 0; fp < 5; ++fp) {
        int lc0 = cq + fp * 32 + l15;
        float b0 = bias[lc0], b1 = bias[lc0 + 16];
        int headg = ch * 10 + (cq >> 5) + fp;
#pragma unroll
        for (int j = 0; j < 4; ++j) {
            int n = n0 + rw + l4 * 4 + j;
            if (n < N_NODES)
                y32[(size_t)n * 320 + headg * 16 + l15] =
                    cvtpk(acc[2 * fp][j] + b0, acc[2 * fp + 1][j] + b1);
        }
    }
}

// B-chunk global fetch for 256-thread edge kernel (2560 uint2 per chunk)
DI uint2 ldB2(const unsigned short* __restrict__ Wh, int kq, int id) {
    int col = id >> 3;
    int k16 = ((id >> 1) & 3) ^ ((col >> 1) & 3);
    return *reinterpret_cast<const uint2*>(
        Wh + (size_t)(640 + col) * 128 + kq * 32 + k16 * 8 + (id & 1) * 4);
}
#define LOADC_E(arr, kq_) do { \
    _Pragma("unroll") \
    for (int s_ = 0; s_ < 10; ++s_) arr[s_] = ldB2(Wh, (kq_), s_ * 256 + tid); \
} while (0)
#define STAGEC_E(arr) do { \
    _Pragma("unroll") \
    for (int s_ = 0; s_ < 10; ++s_) \
        *reinterpret_cast<uint2*>(sB + (s_ * 256 + tid) * 8) = arr[s_]; \
} while (0)
#define GEMM_STEP_E(kq_) do { \
    s16x8 a_ = *reinterpret_cast<const s16x8*>(sA + swzA(rw + l15, (kq_) * 64 + l4 * 16)); \
    _Pragma("unroll") \
    for (int f_ = 0; f_ < 10; ++f_) { \
        int col_ = cq + f_ * 16 + l15; \
        s16x8 b_ = *reinterpret_cast<const s16x8*>( \
            sB + col_ * 64 + ((l4 ^ ((col_ >> 1) & 3)) << 4)); \
        acc[f_] = __builtin_amdgcn_mfma_f32_16x16x32_bf16(a_, b_, acc[f_], 0, 0, 0); \
    } \
} while (0)

// ---------------- edge GEMM + GATv2 scoring: 32-edge tile, 256 threads -----
// 4 waves/block -> 4 independent blocks per CU at the 16-waves/CU reg bracket.
// LDS 28,672B: A [32][256B]=8KB + B chunk 20KB; spill [32][648]=20.7KB aliases.
__global__ __launch_bounds__(256)
void k_edge(const float* __restrict__ eattr, const unsigned short* __restrict__ Wh,
            const unsigned short* __restrict__ y, const int* __restrict__ ei,
            const float* __restrict__ att, float* __restrict__ alphaE,
            float* __restrict__ denom)
{
    __shared__ unsigned char smem[28672];
    unsigned char* sA = smem;                     // A tile (8KB), GEMM phase
    unsigned char* sB = smem + 8192;              // B chunk (20KB), GEMM phase
    unsigned char* sE = smem;                     // ea spill [32][648], after GEMM
    const int tid = threadIdx.x;
    const int e0 = blockIdx.x * 32;
    const int w = tid >> 6, l = tid & 63;         // w 0..3
    const int rw = (w & 1) * 16;                  // 2 row-groups of 16
    const int cq = (w >> 1) * 160;                // 2 col-groups of 160
    const int l15 = l & 15, l4 = l >> 4;
    const unsigned int* y32 = reinterpret_cast<const unsigned int*>(y);

    uint2 bA[10], bB[10];
    LOADC_E(bA, 0);                               // prefetch B chunk 0 first

    // edge endpoints (8 edges per wave, 8 lanes each)
    const int p = l >> 3, q = l & 7;
    const int e = e0 + w * 8 + p;
    const int src = ei[e];
    const int dst = ei[N_EDGES + e];

    // stage A (edge_attr fp32 -> bf16); E = 12500*32 exact
#pragma unroll
    for (int it = 0; it < 4; ++it) {
        int c = tid + it * 256;                   // 0..1023
        int row = c >> 5, qa = c & 31;            // row 0..31
        f32x4 v = __builtin_nontemporal_load(
            reinterpret_cast<const f32x4*>(eattr + (size_t)(e0 + row) * 128 + qa * 4));
        uint2 pk = make_uint2(cvtpk(v[0], v[1]), cvtpk(v[2], v[3]));
        *reinterpret_cast<uint2*>(sA + swzA(row, qa * 8)) = pk;
    }
    LOADC_E(bB, 1);                               // prefetch chunk 1

    f32x4 acc[10];
#pragma unroll
    for (int f = 0; f < 10; ++f) acc[f] = (f32x4){0.f, 0.f, 0.f, 0.f};

    STAGEC_E(bA);  bar_sync();  GEMM_STEP_E(0);   // chunk 0
    LOADC_E(bA, 2);
    bar_sync();                                   // chunk-0 reads done
    STAGEC_E(bB);  bar_sync();  GEMM_STEP_E(1);   // chunk 1
    LOADC_E(bB, 3);
    bar_sync();                                   // chunk-1 reads done
    STAGEC_E(bA);  bar_sync();  GEMM_STEP_E(2);   // chunk 2
    bar_sync();                                   // chunk-2 reads done
    STAGEC_E(bB);  bar_sync();  GEMM_STEP_E(3);   // chunk 3

    // pre-gather xl[src], xr[dst] (overlaps spill + barriers)
    uint4 xg[5], rg[5];
#pragma unroll
    for (int it = 0; it < 5; ++it) {
        int chk = it * 8 + q;
        xg[it] = *reinterpret_cast<const uint4*>(y32 + (size_t)src * 320 + chk * 4);
        rg[it] = *reinterpret_cast<const uint4*>(y32 + (size_t)dst * 320 + 160 + chk * 4);
    }

    bar_sync();   // all MFMA LDS reads done -> safe to overwrite as sE

    // spill ea as paired-bf16 u32s, row stride 648B; rows 0..31
#pragma unroll
    for (int fp = 0; fp < 5; ++fp) {
        int head = (cq >> 5) + fp;                // 0..4 or 5..9
#pragma unroll
        for (int j = 0; j < 4; ++j) {
            int row = rw + l4 * 4 + j;            // 0..31
            *reinterpret_cast<unsigned int*>(sE + row * 648 + (head * 16 + l15) * 4) =
                cvtpk(acc[2 * fp][j], acc[2 * fp + 1][j]);
        }
    }
    bar_sync();

    // ---- scoring: 8 edges/wave x 8 lanes, 5 iterations of 16B chunks ----
    float hv[5];
#pragma unroll
    for (int it = 0; it < 5; ++it) {
        int chk = it * 8 + q;                     // chunk 0..39
        s16x8 ev = *reinterpret_cast<const s16x8*>(sE + (w * 8 + p) * 648 + chk * 16);
        int head = it * 2 + (q >> 2), c4 = q & 3;
        float4 alo = *reinterpret_cast<const float4*>(att + head * 32 + c4 * 4);
        float4 ahi = *reinterpret_cast<const float4*>(att + head * 32 + 16 + c4 * 4);
        const unsigned int* eu  = reinterpret_cast<const unsigned int*>(&ev);
        const unsigned int* xlu = reinterpret_cast<const unsigned int*>(&xg[it]);
        const unsigned int* xru = reinterpret_cast<const unsigned int*>(&rg[it]);
        const float* al = reinterpret_cast<const float*>(&alo);
        const float* ah = reinterpret_cast<const float*>(&ahi);
        float P1 = 0.f, P2 = 0.f;
#pragma unroll
        for (int i = 0; i < 4; ++i) {
            float mlo = lo16(eu[i]) + lo16(xlu[i]) + lo16(xru[i]);
            float mhi = hi16(eu[i]) + hi16(xlu[i]) + hi16(xru[i]);
            P1 = fmaf(al[i], mlo, P1);
            P2 = fmaf(al[i], fabsf(mlo), P2);
            P1 = fmaf(ah[i], mhi, P1);
            P2 = fmaf(ah[i], fabsf(mhi), P2);
        }
        // att.lrelu(m) = 0.6*att.m + 0.4*att.|m| (slope 0.2)
        float v = 0.6f * P1 + 0.4f * P2;
        v += __shfl_xor(v, 1);
        v += __shfl_xor(v, 2);
        hv[it] = v;                               // valid on lanes with (l&3)==0
    }
    if ((l & 3) == 0) {
        int par = (l >> 2) & 1;
#pragma unroll
        for (int it = 0; it < 5; ++it) {
            float ex = __expf(hv[it]);            // |logit| small: no max-shift
            int head = it * 2 + par;
            alphaE[(size_t)e * 10 + head] = ex;
            atomicAdd(&denom[(size_t)dst * 10 + head], ex);
        }
    }
}

// ---------------- aggregation: accC[dst,c] += sum_h xl[src,h,c]*alpha_norm ----
__global__ __launch_bounds__(256)
void k_agg(const float* __restrict__ alphaE, const float* __restrict__ denom,
           const unsigned short* __restrict__ y, const int* __restrict__ ei,
           float* __restrict__ accC)
{
    const int lane = threadIdx.x & 63;
    const int hw = lane >> 5;             // which edge of the pair
    const int hl = lane & 31;
    const int wid = (blockIdx.x * blockDim.x + threadIdx.x) >> 6;
    const int nw = (gridDim.x * blockDim.x) >> 6;
    const unsigned int* y32 = reinterpret_cast<const unsigned int*>(y);
#pragma unroll 2
    for (int ep = wid; ep < N_EDGES / 2; ep += nw) {
        int e = ep * 2 + hw;
        int src = ei[e];
        int dst = ei[N_EDGES + e];
        float wv = 0.f;
        if (hl < 10)
            wv = alphaE[(size_t)e * 10 + hl] / (denom[(size_t)dst * 10 + hl] + 1e-16f);
        float sLO = 0.f, sHI = 0.f;
#pragma unroll
        for (int k = 0; k < 5; ++k) {
            int g = k * 32 + hl;          // u32 index in xl block (0..159)
            float wh = __shfl(wv, (hw << 5) | (k * 2 + (hl >> 4)));
            unsigned int u = y32[(size_t)src * 320 + g];
            sLO = fmaf(wh, lo16(u), sLO);
            sHI = fmaf(wh, hi16(u), sHI);
        }
        sLO += __shfl_xor(sLO, 16);
        sHI += __shfl_xor(sHI, 16);
        atomicAdd(&accC[(size_t)dst * 32 + hl], (hl & 16) ? sHI : sLO);
    }
}

// ---------------- per-node finish + per-graph mean pool ----------------
__global__ __launch_bounds__(256)
void k_pool(const float* __restrict__ accC, const float* __restrict__ bias_out,
            const int* __restrict__ batch, float* __restrict__ pooled,
            float* __restrict__ cnt)
{
    __shared__ float sm[G * C];
    __shared__ float smc[G];
    int tid = threadIdx.x;
    for (int i = tid; i < G * C; i += 256) sm[i] = 0.f;
    if (tid < G) smc[tid] = 0.f;
    __syncthreads();
    int base = blockIdx.x * 2048;
    for (int it = 0; it < 8; ++it) {
        int idx = base + it * 256 + tid;
        if (idx < N_NODES * C) {
            int n = idx >> 5, c = idx & 31;
            float v = accC[idx] * 0.1f + bias_out[c];
            v = fmaxf(v, 0.f);
            int gr = batch[n];
            atomicAdd(&sm[gr * C + c], v);
            if (c == 0) atomicAdd(&smc[gr], 1.f);
        }
    }
    __syncthreads();
    for (int i = tid; i < G * C; i += 256)
        if (sm[i] != 0.f) atomicAdd(&pooled[i], sm[i]);
    if (tid < G && smc[tid] != 0.f) atomicAdd(&cnt[tid], smc[tid]);
}

// ---------------- final tiny classifier ----------------
__global__ void k_final(const float* __restrict__ pooled, const float* __restrict__ cnt,
                        const float* __restrict__ Wlin, const float* __restrict__ blin,
                        float* __restrict__ out)
{
    int g = threadIdx.x;
    if (g >= G) return;
    float cg = fmaxf(cnt[g], 1.f);
    float s0 = blin[0], s1 = blin[1];
#pragma unroll
    for (int c = 0; c < C; ++c) {
        float p = pooled[g * C + c] / cg;
        s0 += p * Wlin[c];
        s1 += p * Wlin[C + c];
    }
    out[g * 2 + 0] = s0;
    out[g * 2 + 1] = s1;
}

extern "C" void kernel_launch(void* const* d_in, const int* in_sizes, int n_in,
                              void* d_out, int out_size, void* d_ws, size_t ws_size,
                              hipStream_t stream)
{
    const float* x         = (const float*)d_in[0];
    const float* edge_attr = (const float*)d_in[1];
    const float* bn_gamma  = (const float*)d_in[2];
    const float* bn_beta   = (const float*)d_in[3];
    const float* bn_mean   = (const float*)d_in[4];
    const float* bn_var    = (const float*)d_in[5];
    const float* Wl        = (const float*)d_in[6];
    const float* bl        = (const float*)d_in[7];
    const float* Wr        = (const float*)d_in[8];
    const float* br        = (const float*)d_in[9];
    const float* We        = (const float*)d_in[10];
    const float* att       = (const float*)d_in[11];
    const float* bias_out  = (const float*)d_in[12];
    const float* Wlin      = (const float*)d_in[13];
    const float* blin      = (const float*)d_in[14];
    const int* edge_index  = (const int*)d_in[15];
    const int* batch       = (const int*)d_in[16];
    float* out = (float*)d_out;

    char* ws = (char*)d_ws;
    unsigned short* Wh    = (unsigned short*)(ws + OFF_WH);
    float* scale          = (float*)(ws + OFF_SCALE);
    float* shift          = (float*)(ws + OFF_SHIFT);
    unsigned short* y     = (unsigned short*)(ws + OFF_Y);
    float* alphaE         = (float*)(ws + OFF_ALPHA);
    float* denom          = (float*)(ws + OFF_DENOM);
    float* accC           = (float*)(ws + OFF_ACC);
    float* pooled         = (float*)(ws + OFF_POOL);
    float* cnt            = (float*)(ws + OFF_CNT);

    k_init<<<1024, 256, 0, stream>>>(Wl, Wr, We, bn_gamma, bn_beta, bn_mean, bn_var,
                                     Wh, scale, shift, denom, accC, pooled, cnt);
    k_node_gemm<<<dim3(782, 2), 512, 0, stream>>>(x, Wh, scale, shift, bl, br, y);
    k_edge<<<12500, 256, 0, stream>>>(edge_attr, Wh, y, edge_index, att, alphaE, denom);
    k_agg<<<2048, 256, 0, stream>>>(alphaE, denom, y, edge_index, accC);
    k_pool<<<782, 256, 0, stream>>>(accC, bias_out, batch, pooled, cnt);
    k_final<<<1, 64, 0, stream>>>(pooled, cnt, Wlin, blin, out);
}

// Round 13
// 274.665 us; speedup vs baseline: 1.0459x; 1.0459x over previous
//
#include <hip/hip_runtime.h>
#include <hip/hip_bf16.h>

#define DI __device__ __forceinline__

typedef float f32x4 __attribute__((ext_vector_type(4)));
typedef short s16x8 __attribute__((ext_vector_type(8)));

constexpr int N_NODES = 50000;
constexpr int N_EDGES = 400000;
constexpr int G       = 64;
constexpr int C       = 32;
constexpr float BN_EPS = 1e-5f;

// ---------------- workspace layout (bytes) ----------------
constexpr size_t OFF_WH    = 0;                                   // [960][128] bf16 (Wl,Wr,We)
constexpr size_t OFF_SCALE = 245760;                              // [128] f32
constexpr size_t OFF_SHIFT = OFF_SCALE + 512;                     // [128] f32
constexpr size_t OFF_Y     = OFF_SHIFT + 512;                     // [N][640] bf16 (xl|xr, PAIRED)
constexpr size_t OFF_ALPHA = OFF_Y + (size_t)N_NODES * 640 * 2;   // [E][10] f32 (exp(alpha))
constexpr size_t OFF_DENOM = OFF_ALPHA + (size_t)N_EDGES * 10 * 4;// [N][10] f32
constexpr size_t OFF_ACC   = OFF_DENOM + (size_t)N_NODES * 10 * 4;// [N][32] f32
constexpr size_t OFF_POOL  = OFF_ACC + (size_t)N_NODES * 32 * 4;  // [64][32] f32
constexpr size_t OFF_CNT   = OFF_POOL + (size_t)G * C * 4;        // [64] f32

// y PAIRED layout: u32[n*320 + headg*16 + s] holds bf16 cols (headg*32+s, headg*32+16+s),
// headg 0..9 = xl heads, 10..19 = xr heads.

DI float bf2f(unsigned short u) {
    unsigned int x = ((unsigned int)u) << 16;
    float f; __builtin_memcpy(&f, &x, 4); return f;
}
DI unsigned short f2bf(float f) {
    unsigned int x; __builtin_memcpy(&x, &f, 4);
    x += 0x7FFFu + ((x >> 16) & 1u);
    return (unsigned short)(x >> 16);
}
DI float lo16(unsigned int u) {
    unsigned int x = u << 16; float f; __builtin_memcpy(&f, &x, 4); return f;
}
DI float hi16(unsigned int u) {
    unsigned int x = u & 0xffff0000u; float f; __builtin_memcpy(&f, &x, 4); return f;
}
DI unsigned int cvtpk(float a, float b) {  // v_cvt_pk_bf16_f32: lo=a, hi=b
    unsigned int r;
    asm("v_cvt_pk_bf16_f32 %0, %1, %2" : "=v"(r) : "v"(a), "v"(b));
    return r;
}
// XOR swizzle inside a 256B row (A tile: row stride 256B)
DI int swzA(int row, int kb) { return row * 256 + (kb ^ ((row & 7) << 4)); }

// raw barrier: drain LDS only, leave global prefetches in flight
DI void bar_sync() {
    __builtin_amdgcn_sched_barrier(0);
    asm volatile("s_waitcnt lgkmcnt(0)" ::: "memory");
    __builtin_amdgcn_s_barrier();
    __builtin_amdgcn_sched_barrier(0);
}

// ---------------- init ----------------
__global__ void k_init(const float* __restrict__ Wl, const float* __restrict__ Wr,
                       const float* __restrict__ We, const float* __restrict__ gamma,
                       const float* __restrict__ beta, const float* __restrict__ mean,
                       const float* __restrict__ var,
                       unsigned short* __restrict__ Wh, float* __restrict__ scale,
                       float* __restrict__ shift, float* __restrict__ denom,
                       float* __restrict__ accC, float* __restrict__ pooled,
                       float* __restrict__ cnt)
{
    int idx0 = blockIdx.x * blockDim.x + threadIdx.x;
    int stride = gridDim.x * blockDim.x;
    for (int i = idx0; i < 960 * 128; i += stride) {
        float v;
        if (i < 320 * 128)      v = Wl[i];
        else if (i < 640 * 128) v = Wr[i - 320 * 128];
        else                    v = We[i - 640 * 128];
        Wh[i] = f2bf(v);
    }
    for (int i = idx0; i < 128; i += stride) {
        float sc = gamma[i] * rsqrtf(var[i] + BN_EPS);
        scale[i] = sc;
        shift[i] = beta[i] - mean[i] * sc;
    }
    for (int i = idx0; i < N_NODES * 10; i += stride) denom[i] = 0.f;
    for (int i = idx0; i < N_NODES * 32; i += stride) accC[i] = 0.f;
    for (int i = idx0; i < G * C; i += stride) pooled[i] = 0.f;
    for (int i = idx0; i < G; i += stride) cnt[i] = 0.f;
}

// ---------------- node GEMM (R6-bench proven: 4-chunk restage) --------
// B-chunk LDS layout: slot (col,k16') at byte col*64+k16'*16 holds global
// k-frag k16 = k16' ^ ((col>>1)&3). Writes linear; reads 2-way max.
__global__ __launch_bounds__(512)
void k_node_gemm(const float* __restrict__ x, const unsigned short* __restrict__ Wh,
                 const float* __restrict__ scale, const float* __restrict__ shift,
                 const float* __restrict__ bl, const float* __restrict__ br,
                 unsigned short* __restrict__ y)
{
    __shared__ unsigned char smem[36864];
    unsigned char* sA = smem;             // [64][256B] swizzled
    unsigned char* sB = smem + 16384;     // B chunk, 20KB
    const int tid = threadIdx.x;
    const int n0 = blockIdx.x * 64;
    const int ch = blockIdx.y;            // 0: Wl half, 1: Wr half
    const int wrow0n = ch * 320;

    // stage A (x with BN fused), fp32 -> bf16
#pragma unroll
    for (int it = 0; it < 4; ++it) {
        int c = tid + it * 512;           // 0..2047
        int row = c >> 5, q = c & 31;
        int n = n0 + row;
        f32x4 v = (f32x4){0.f, 0.f, 0.f, 0.f};
        if (n < N_NODES)
            v = __builtin_nontemporal_load(
                reinterpret_cast<const f32x4*>(x + (size_t)n * 128 + q * 4));
        float x0 = v[0] * scale[q * 4 + 0] + shift[q * 4 + 0];
        float x1 = v[1] * scale[q * 4 + 1] + shift[q * 4 + 1];
        float x2 = v[2] * scale[q * 4 + 2] + shift[q * 4 + 2];
        float x3 = v[3] * scale[q * 4 + 3] + shift[q * 4 + 3];
        uint2 pk = make_uint2(cvtpk(x0, x1), cvtpk(x2, x3));
        *reinterpret_cast<uint2*>(sA + swzA(row, q * 8)) = pk;
    }

    const int w = tid >> 6, l = tid & 63;
    const int rw = (w & 3) * 16;
    const int cq = (w >> 2) * 160;
    const int l15 = l & 15, l4 = l >> 4;

    f32x4 acc[10];
#pragma unroll
    for (int f = 0; f < 10; ++f) acc[f] = (f32x4){0.f, 0.f, 0.f, 0.f};

    for (int kq = 0; kq < 4; ++kq) {
        __syncthreads();                  // A ready (kq=0) / prev MFMA done (kq>0)
#pragma unroll
        for (int it = 0; it < 3; ++it) {
            int id = tid + it * 512;      // 0..1535, valid < 1280
            if (id < 1280) {
                int col = id >> 2;
                int k16 = (id & 3) ^ ((col >> 1) & 3);
                uint4 v = *reinterpret_cast<const uint4*>(
                    Wh + (size_t)(wrow0n + col) * 128 + kq * 32 + k16 * 8);
                *reinterpret_cast<uint4*>(sB + id * 16) = v;
            }
        }
        __syncthreads();
        s16x8 a = *reinterpret_cast<const s16x8*>(sA + swzA(rw + l15, kq * 64 + l4 * 16));
#pragma unroll
        for (int f = 0; f < 10; ++f) {
            int col = cq + f * 16 + l15;
            s16x8 b = *reinterpret_cast<const s16x8*>(
                sB + col * 64 + ((l4 ^ ((col >> 1) & 3)) << 4));
            acc[f] = __builtin_amdgcn_mfma_f32_16x16x32_bf16(a, b, acc[f], 0, 0, 0);
        }
    }

    const float* bias = ch ? br : bl;
    unsigned int* y32 = reinterpret_cast<unsigned int*>(y);
#pragma unroll
    for (int fp = 0; fp < 5; ++fp) {
        int lc0 = cq + fp * 32 + l15;
        float b0 = bias[lc0], b1 = bias[lc0 + 16];
        int headg = ch * 10 + (cq >> 5) + fp;
#pragma unroll
        for (int j = 0; j < 4; ++j) {
            int n = n0 + rw + l4 * 4 + j;
            if (n < N_NODES)
                y32[(size_t)n * 320 + headg * 16 + l15] =
                    cvtpk(acc[2 * fp][j] + b0, acc[2 * fp + 1][j] + b1);
        }
    }
}

// B-chunk global fetch: uint2 id -> (col=id>>3, k16'=(id>>1)&3, half=id&1),
// global k-frag k16 = k16' ^ ((col>>1)&3)  (conflict-free LDS layout)
DI uint2 ldB(const unsigned short* Wh, int wrow0, int kq, int s, int tid) {
    int id = s * 512 + tid;
    int col = id >> 3;
    int k16 = ((id >> 1) & 3) ^ ((col >> 1) & 3);
    return *reinterpret_cast<const uint2*>(
        Wh + (size_t)(wrow0 + col) * 128 + kq * 32 + k16 * 8 + (id & 1) * 4);
}

#define LOADC(arr, kq_) do { \
    _Pragma("unroll") \
    for (int s_ = 0; s_ < 5; ++s_) arr[s_] = ldB(Wh, wrow0, (kq_), s_, tid); \
} while (0)

#define STAGEC(arr, buf_) do { \
    _Pragma("unroll") \
    for (int s_ = 0; s_ < 5; ++s_) \
        *reinterpret_cast<uint2*>((buf_) + (s_ * 512 + tid) * 8) = arr[s_]; \
} while (0)

#define GEMM_STEP(kq_, buf_) do { \
    s16x8 a_ = *reinterpret_cast<const s16x8*>(sA + swzA(rw + l15, (kq_) * 64 + l4 * 16)); \
    _Pragma("unroll") \
    for (int f_ = 0; f_ < 10; ++f_) { \
        int col_ = cq + f_ * 16 + l15; \
        s16x8 b_ = *reinterpret_cast<const s16x8*>( \
            (buf_) + col_ * 64 + ((l4 ^ ((col_ >> 1) & 3)) << 4)); \
        acc[f_] = __builtin_amdgcn_mfma_f32_16x16x32_bf16(a_, b_, acc[f_], 0, 0, 0); \
    } \
} while (0)

// ---------------- edge GEMM + GATv2 scoring (R8-proven, fastest: 172us) -----
// A 16KB + B dbuf 2x20KB = 57344B (2 blocks/CU); spill [64][648] aliases
// bytes 15872..57344. B reg-prefetched; raw lgkm barriers keep loads in flight.
__global__ __launch_bounds__(512)
void k_edge(const float* __restrict__ eattr, const unsigned short* __restrict__ Wh,
            const unsigned short* __restrict__ y, const int* __restrict__ ei,
            const float* __restrict__ att, float* __restrict__ alphaE,
            float* __restrict__ denom)
{
    __shared__ unsigned char smem[57344];
    unsigned char* sA   = smem;
    unsigned char* buf0 = smem + 16384;
    unsigned char* buf1 = smem + 36864;
    unsigned char* sE   = smem + 15872;           // spill, after GEMM
    const int tid = threadIdx.x;
    const int e0 = blockIdx.x * 64;
    const int w = tid >> 6, l = tid & 63;
    const int rw = (w & 3) * 16;
    const int cq = (w >> 2) * 160;
    const int l15 = l & 15, l4 = l >> 4;
    const int wrow0 = 640;                        // We rows in Wh
    const unsigned int* y32 = reinterpret_cast<const unsigned int*>(y);

    uint2 bA[5], bB[5];
    LOADC(bA, 0);                                 // prefetch B chunk 0 first

    // edge endpoints (issued at entry; consumed by pre-gather after GEMM)
    const int p = l >> 3, q = l & 7;
    const int e = e0 + w * 8 + p;
    const int src = ei[e];
    const int dst = ei[N_EDGES + e];

    // stage A (edge_attr fp32 -> bf16, nontemporal stream); E = 6250*64 exact
#pragma unroll
    for (int it = 0; it < 4; ++it) {
        int c = tid + it * 512;
        int row = c >> 5, qa = c & 31;
        f32x4 v = __builtin_nontemporal_load(
            reinterpret_cast<const f32x4*>(eattr + (size_t)(e0 + row) * 128 + qa * 4));
        uint2 pk = make_uint2(cvtpk(v[0], v[1]), cvtpk(v[2], v[3]));
        *reinterpret_cast<uint2*>(sA + swzA(row, qa * 8)) = pk;
    }

    f32x4 acc[10];
#pragma unroll
    for (int f = 0; f < 10; ++f) acc[f] = (f32x4){0.f, 0.f, 0.f, 0.f};

    LOADC(bB, 1); STAGEC(bA, buf0); bar_sync(); GEMM_STEP(0, buf0);
    LOADC(bA, 2); STAGEC(bB, buf1); bar_sync(); GEMM_STEP(1, buf1);
    LOADC(bB, 3); STAGEC(bA, buf0); bar_sync(); GEMM_STEP(2, buf0);
                  STAGEC(bB, buf1); bar_sync(); GEMM_STEP(3, buf1);

    // pre-gather xl[src], xr[dst] (overlaps spill + barriers)
    uint4 xg[5], rg[5];
#pragma unroll
    for (int it = 0; it < 5; ++it) {
        int chk = it * 8 + q;
        xg[it] = *reinterpret_cast<const uint4*>(y32 + (size_t)src * 320 + chk * 4);
        rg[it] = *reinterpret_cast<const uint4*>(y32 + (size_t)dst * 320 + 160 + chk * 4);
    }

    bar_sync();   // all MFMA LDS reads done -> safe to overwrite as sE

    // spill ea as paired-bf16 u32s, row stride 648B
#pragma unroll
    for (int fp = 0; fp < 5; ++fp) {
        int head = (cq >> 5) + fp;        // 0..9
#pragma unroll
        for (int j = 0; j < 4; ++j) {
            int row = rw + l4 * 4 + j;
            *reinterpret_cast<unsigned int*>(sE + row * 648 + (head * 16 + l15) * 4) =
                cvtpk(acc[2 * fp][j], acc[2 * fp + 1][j]);
        }
    }
    bar_sync();

    // ---- scoring: 64 lanes = 8 edges x 8 lanes, 5 iterations of 16B chunks ----
    float hv[5];
#pragma unroll
    for (int it = 0; it < 5; ++it) {
        int chk = it * 8 + q;             // chunk 0..39
        s16x8 ev = *reinterpret_cast<const s16x8*>(sE + (w * 8 + p) * 648 + chk * 16);
        int head = it * 2 + (q >> 2), c4 = q & 3;
        float4 alo = *reinterpret_cast<const float4*>(att + head * 32 + c4 * 4);
        float4 ahi = *reinterpret_cast<const float4*>(att + head * 32 + 16 + c4 * 4);
        const unsigned int* eu  = reinterpret_cast<const unsigned int*>(&ev);
        const unsigned int* xlu = reinterpret_cast<const unsigned int*>(&xg[it]);
        const unsigned int* xru = reinterpret_cast<const unsigned int*>(&rg[it]);
        const float* al = reinterpret_cast<const float*>(&alo);
        const float* ah = reinterpret_cast<const float*>(&ahi);
        float P1 = 0.f, P2 = 0.f;
#pragma unroll
        for (int i = 0; i < 4; ++i) {
            float mlo = lo16(eu[i]) + lo16(xlu[i]) + lo16(xru[i]);
            float mhi = hi16(eu[i]) + hi16(xlu[i]) + hi16(xru[i]);
            P1 = fmaf(al[i], mlo, P1);
            P2 = fmaf(al[i], fabsf(mlo), P2);
            P1 = fmaf(ah[i], mhi, P1);
            P2 = fmaf(ah[i], fabsf(mhi), P2);
        }
        // att.lrelu(m) = 0.6*att.m + 0.4*att.|m| (slope 0.2)
        float v = 0.6f * P1 + 0.4f * P2;
        v += __shfl_xor(v, 1);
        v += __shfl_xor(v, 2);
        hv[it] = v;                       // valid on lanes with (l&3)==0
    }
    if ((l & 3) == 0) {
        int par = (l >> 2) & 1;
#pragma unroll
        for (int it = 0; it < 5; ++it) {
            float ex = __expf(hv[it]);    // |logit| small: no max-shift needed
            int head = it * 2 + par;
            alphaE[(size_t)e * 10 + head] = ex;
            atomicAdd(&denom[(size_t)dst * 10 + head], ex);
        }
    }
}

// ---------------- aggregation: accC[dst,c] += sum_h xl[src,h,c]*alpha_norm ----
// single-touch streams (ei, alphaE) use nontemporal loads to preserve L2/L3
// for the reused y rows and denom entries.
__global__ __launch_bounds__(256)
void k_agg(const float* __restrict__ alphaE, const float* __restrict__ denom,
           const unsigned short* __restrict__ y, const int* __restrict__ ei,
           float* __restrict__ accC)
{
    const int lane = threadIdx.x & 63;
    const int hw = lane >> 5;             // which edge of the pair
    const int hl = lane & 31;
    const int wid = (blockIdx.x * blockDim.x + threadIdx.x) >> 6;
    const int nw = (gridDim.x * blockDim.x) >> 6;
    const unsigned int* y32 = reinterpret_cast<const unsigned int*>(y);
#pragma unroll 4
    for (int ep = wid; ep < N_EDGES / 2; ep += nw) {
        int e = ep * 2 + hw;
        int src = __builtin_nontemporal_load(ei + e);
        int dst = __builtin_nontemporal_load(ei + N_EDGES + e);
        float wv = 0.f;
        if (hl < 10)
            wv = __builtin_nontemporal_load(alphaE + (size_t)e * 10 + hl) /
                 (denom[(size_t)dst * 10 + hl] + 1e-16f);
        float sLO = 0.f, sHI = 0.f;
#pragma unroll
        for (int k = 0; k < 5; ++k) {
            int g = k * 32 + hl;          // u32 index in xl block (0..159)
            float wh = __shfl(wv, (hw << 5) | (k * 2 + (hl >> 4)));
            unsigned int u = y32[(size_t)src * 320 + g];
            sLO = fmaf(wh, lo16(u), sLO);
            sHI = fmaf(wh, hi16(u), sHI);
        }
        sLO += __shfl_xor(sLO, 16);
        sHI += __shfl_xor(sHI, 16);
        atomicAdd(&accC[(size_t)dst * 32 + hl], (hl & 16) ? sHI : sLO);
    }
}

// ---------------- per-node finish + per-graph mean pool ----------------
__global__ __launch_bounds__(256)
void k_pool(const float* __restrict__ accC, const float* __restrict__ bias_out,
            const int* __restrict__ batch, float* __restrict__ pooled,
            float* __restrict__ cnt)
{
    __shared__ float sm[G * C];
    __shared__ float smc[G];
    int tid = threadIdx.x;
    for (int i = tid; i < G * C; i += 256) sm[i] = 0.f;
    if (tid < G) smc[tid] = 0.f;
    __syncthreads();
    int base = blockIdx.x * 2048;
    for (int it = 0; it < 8; ++it) {
        int idx = base + it * 256 + tid;
        if (idx < N_NODES * C) {
            int n = idx >> 5, c = idx & 31;
            float v = __builtin_nontemporal_load(accC + idx) * 0.1f + bias_out[c];
            v = fmaxf(v, 0.f);
            int gr = batch[n];
            atomicAdd(&sm[gr * C + c], v);
            if (c == 0) atomicAdd(&smc[gr], 1.f);
        }
    }
    __syncthreads();
    for (int i = tid; i < G * C; i += 256)
        if (sm[i] != 0.f) atomicAdd(&pooled[i], sm[i]);
    if (tid < G && smc[tid] != 0.f) atomicAdd(&cnt[tid], smc[tid]);
}

// ---------------- final tiny classifier ----------------
__global__ void k_final(const float* __restrict__ pooled, const float* __restrict__ cnt,
                        const float* __restrict__ Wlin, const float* __restrict__ blin,
                        float* __restrict__ out)
{
    int g = threadIdx.x;
    if (g >= G) return;
    float cg = fmaxf(cnt[g], 1.f);
    float s0 = blin[0], s1 = blin[1];
#pragma unroll
    for (int c = 0; c < C; ++c) {
        float p = pooled[g * C + c] / cg;
        s0 += p * Wlin[c];
        s1 += p * Wlin[C + c];
    }
    out[g * 2 + 0] = s0;
    out[g * 2 + 1] = s1;
}

extern "C" void kernel_launch(void* const* d_in, const int* in_sizes, int n_in,
                              void* d_out, int out_size, void* d_ws, size_t ws_size,
                              hipStream_t stream)
{
    const float* x         = (const float*)d_in[0];
    const float* edge_attr = (const float*)d_in[1];
    const float* bn_gamma  = (const float*)d_in[2];
    const float* bn_beta   = (const float*)d_in[3];
    const float* bn_mean   = (const float*)d_in[4];
    const float* bn_var    = (const float*)d_in[5];
    const float* Wl        = (const float*)d_in[6];
    const float* bl        = (const float*)d_in[7];
    const float* Wr        = (const float*)d_in[8];
    const float* br        = (const float*)d_in[9];
    const float* We        = (const float*)d_in[10];
    const float* att       = (const float*)d_in[11];
    const float* bias_out  = (const float*)d_in[12];
    const float* Wlin      = (const float*)d_in[13];
    const float* blin      = (const float*)d_in[14];
    const int* edge_index  = (const int*)d_in[15];
    const int* batch       = (const int*)d_in[16];
    float* out = (float*)d_out;

    char* ws = (char*)d_ws;
    unsigned short* Wh    = (unsigned short*)(ws + OFF_WH);
    float* scale          = (float*)(ws + OFF_SCALE);
    float* shift          = (float*)(ws + OFF_SHIFT);
    unsigned short* y     = (unsigned short*)(ws + OFF_Y);
    float* alphaE         = (float*)(ws + OFF_ALPHA);
    float* denom          = (float*)(ws + OFF_DENOM);
    float* accC           = (float*)(ws + OFF_ACC);
    float* pooled         = (float*)(ws + OFF_POOL);
    float* cnt            = (float*)(ws + OFF_CNT);

    k_init<<<1024, 256, 0, stream>>>(Wl, Wr, We, bn_gamma, bn_beta, bn_mean, bn_var,
                                     Wh, scale, shift, denom, accC, pooled, cnt);
    k_node_gemm<<<dim3(782, 2), 512, 0, stream>>>(x, Wh, scale, shift, bl, br, y);
    k_edge<<<6250, 512, 0, stream>>>(edge_attr, Wh, y, edge_index, att, alphaE, denom);
    k_agg<<<2048, 256, 0, stream>>>(alphaE, denom, y, edge_index, accC);
    k_pool<<<782, 256, 0, stream>>>(accC, bias_out, batch, pooled, cnt);
    k_final<<<1, 64, 0, stream>>>(pooled, cnt, Wlin, blin, out);
}

// Round 14
// 267.963 us; speedup vs baseline: 1.0720x; 1.0250x over previous
//
#include <hip/hip_runtime.h>
#include <hip/hip_bf16.h>

#define DI __device__ __forceinline__

typedef float f32x4 __attribute__((ext_vector_type(4)));
typedef short s16x8 __attribute__((ext_vector_type(8)));

constexpr int N_NODES = 50000;
constexpr int N_EDGES = 400000;
constexpr int G       = 64;
constexpr int C       = 32;
constexpr float BN_EPS = 1e-5f;

// ---------------- workspace layout (bytes) ----------------
constexpr size_t OFF_WH    = 0;                                   // [960][128] bf16 (Wl,Wr,We)
constexpr size_t OFF_SCALE = 245760;                              // [128] f32
constexpr size_t OFF_SHIFT = OFF_SCALE + 512;                     // [128] f32
constexpr size_t OFF_Y     = OFF_SHIFT + 512;                     // [N][640] bf16 (xl|xr, PAIRED)
constexpr size_t OFF_ALPHA = OFF_Y + (size_t)N_NODES * 640 * 2;   // [E][10] f32 (exp(alpha))
constexpr size_t OFF_DENOM = OFF_ALPHA + (size_t)N_EDGES * 10 * 4;// [N][10] f32
constexpr size_t OFF_ACC   = OFF_DENOM + (size_t)N_NODES * 10 * 4;// [N][32] f32
constexpr size_t OFF_POOL  = OFF_ACC + (size_t)N_NODES * 32 * 4;  // [64][32] f32
constexpr size_t OFF_CNT   = OFF_POOL + (size_t)G * C * 4;        // [64] f32

// y PAIRED layout: u32[n*320 + headg*16 + s] holds bf16 cols (headg*32+s, headg*32+16+s),
// headg 0..9 = xl heads, 10..19 = xr heads.

DI float bf2f(unsigned short u) {
    unsigned int x = ((unsigned int)u) << 16;
    float f; __builtin_memcpy(&f, &x, 4); return f;
}
DI unsigned short f2bf(float f) {
    unsigned int x; __builtin_memcpy(&x, &f, 4);
    x += 0x7FFFu + ((x >> 16) & 1u);
    return (unsigned short)(x >> 16);
}
DI float lo16(unsigned int u) {
    unsigned int x = u << 16; float f; __builtin_memcpy(&f, &x, 4); return f;
}
DI float hi16(unsigned int u) {
    unsigned int x = u & 0xffff0000u; float f; __builtin_memcpy(&f, &x, 4); return f;
}
DI unsigned int cvtpk(float a, float b) {  // v_cvt_pk_bf16_f32: lo=a, hi=b
    unsigned int r;
    asm("v_cvt_pk_bf16_f32 %0, %1, %2" : "=v"(r) : "v"(a), "v"(b));
    return r;
}
// XOR swizzle inside a 256B row (A tile: row stride 256B)
DI int swzA(int row, int kb) { return row * 256 + (kb ^ ((row & 7) << 4)); }

// raw barrier: drain LDS only, leave global prefetches in flight
DI void bar_sync() {
    __builtin_amdgcn_sched_barrier(0);
    asm volatile("s_waitcnt lgkmcnt(0)" ::: "memory");
    __builtin_amdgcn_s_barrier();
    __builtin_amdgcn_sched_barrier(0);
}

// ---------------- init ----------------
__global__ void k_init(const float* __restrict__ Wl, const float* __restrict__ Wr,
                       const float* __restrict__ We, const float* __restrict__ gamma,
                       const float* __restrict__ beta, const float* __restrict__ mean,
                       const float* __restrict__ var,
                       unsigned short* __restrict__ Wh, float* __restrict__ scale,
                       float* __restrict__ shift, float* __restrict__ denom,
                       float* __restrict__ accC, float* __restrict__ pooled,
                       float* __restrict__ cnt)
{
    int idx0 = blockIdx.x * blockDim.x + threadIdx.x;
    int stride = gridDim.x * blockDim.x;
    for (int i = idx0; i < 960 * 128; i += stride) {
        float v;
        if (i < 320 * 128)      v = Wl[i];
        else if (i < 640 * 128) v = Wr[i - 320 * 128];
        else                    v = We[i - 640 * 128];
        Wh[i] = f2bf(v);
    }
    for (int i = idx0; i < 128; i += stride) {
        float sc = gamma[i] * rsqrtf(var[i] + BN_EPS);
        scale[i] = sc;
        shift[i] = beta[i] - mean[i] * sc;
    }
    for (int i = idx0; i < N_NODES * 10; i += stride) denom[i] = 0.f;
    for (int i = idx0; i < N_NODES * 32; i += stride) accC[i] = 0.f;
    for (int i = idx0; i < G * C; i += stride) pooled[i] = 0.f;
    for (int i = idx0; i < G; i += stride) cnt[i] = 0.f;
}

// ---------------- node GEMM (R6-bench proven: 4-chunk restage) --------
// B-chunk LDS layout: slot (col,k16') at byte col*64+k16'*16 holds global
// k-frag k16 = k16' ^ ((col>>1)&3). Writes linear; reads 2-way max.
__global__ __launch_bounds__(512)
void k_node_gemm(const float* __restrict__ x, const unsigned short* __restrict__ Wh,
                 const float* __restrict__ scale, const float* __restrict__ shift,
                 const float* __restrict__ bl, const float* __restrict__ br,
                 unsigned short* __restrict__ y)
{
    __shared__ unsigned char smem[36864];
    unsigned char* sA = smem;             // [64][256B] swizzled
    unsigned char* sB = smem + 16384;     // B chunk, 20KB
    const int tid = threadIdx.x;
    const int n0 = blockIdx.x * 64;
    const int ch = blockIdx.y;            // 0: Wl half, 1: Wr half
    const int wrow0n = ch * 320;

    // stage A (x with BN fused), fp32 -> bf16
#pragma unroll
    for (int it = 0; it < 4; ++it) {
        int c = tid + it * 512;           // 0..2047
        int row = c >> 5, q = c & 31;
        int n = n0 + row;
        f32x4 v = (f32x4){0.f, 0.f, 0.f, 0.f};
        if (n < N_NODES)
            v = __builtin_nontemporal_load(
                reinterpret_cast<const f32x4*>(x + (size_t)n * 128 + q * 4));
        float x0 = v[0] * scale[q * 4 + 0] + shift[q * 4 + 0];
        float x1 = v[1] * scale[q * 4 + 1] + shift[q * 4 + 1];
        float x2 = v[2] * scale[q * 4 + 2] + shift[q * 4 + 2];
        float x3 = v[3] * scale[q * 4 + 3] + shift[q * 4 + 3];
        uint2 pk = make_uint2(cvtpk(x0, x1), cvtpk(x2, x3));
        *reinterpret_cast<uint2*>(sA + swzA(row, q * 8)) = pk;
    }

    const int w = tid >> 6, l = tid & 63;
    const int rw = (w & 3) * 16;
    const int cq = (w >> 2) * 160;
    const int l15 = l & 15, l4 = l >> 4;

    f32x4 acc[10];
#pragma unroll
    for (int f = 0; f < 10; ++f) acc[f] = (f32x4){0.f, 0.f, 0.f, 0.f};

    for (int kq = 0; kq < 4; ++kq) {
        __syncthreads();                  // A ready (kq=0) / prev MFMA done (kq>0)
#pragma unroll
        for (int it = 0; it < 3; ++it) {
            int id = tid + it * 512;      // 0..1535, valid < 1280
            if (id < 1280) {
                int col = id >> 2;
                int k16 = (id & 3) ^ ((col >> 1) & 3);
                uint4 v = *reinterpret_cast<const uint4*>(
                    Wh + (size_t)(wrow0n + col) * 128 + kq * 32 + k16 * 8);
                *reinterpret_cast<uint4*>(sB + id * 16) = v;
            }
        }
        __syncthreads();
        s16x8 a = *reinterpret_cast<const s16x8*>(sA + swzA(rw + l15, kq * 64 + l4 * 16));
#pragma unroll
        for (int f = 0; f < 10; ++f) {
            int col = cq + f * 16 + l15;
            s16x8 b = *reinterpret_cast<const s16x8*>(
                sB + col * 64 + ((l4 ^ ((col >> 1) & 3)) << 4));
            acc[f] = __builtin_amdgcn_mfma_f32_16x16x32_bf16(a, b, acc[f], 0, 0, 0);
        }
    }

    const float* bias = ch ? br : bl;
    unsigned int* y32 = reinterpret_cast<unsigned int*>(y);
#pragma unroll
    for (int fp = 0; fp < 5; ++fp) {
        int lc0 = cq + fp * 32 + l15;
        float b0 = bias[lc0], b1 = bias[lc0 + 16];
        int headg = ch * 10 + (cq >> 5) + fp;
#pragma unroll
        for (int j = 0; j < 4; ++j) {
            int n = n0 + rw + l4 * 4 + j;
            if (n < N_NODES)
                y32[(size_t)n * 320 + headg * 16 + l15] =
                    cvtpk(acc[2 * fp][j] + b0, acc[2 * fp + 1][j] + b1);
        }
    }
}

// B-chunk global fetch: uint2 id -> (col=id>>3, k16'=(id>>1)&3, half=id&1),
// global k-frag k16 = k16' ^ ((col>>1)&3)  (conflict-free LDS layout)
DI uint2 ldB(const unsigned short* Wh, int wrow0, int kq, int s, int tid) {
    int id = s * 512 + tid;
    int col = id >> 3;
    int k16 = ((id >> 1) & 3) ^ ((col >> 1) & 3);
    return *reinterpret_cast<const uint2*>(
        Wh + (size_t)(wrow0 + col) * 128 + kq * 32 + k16 * 8 + (id & 1) * 4);
}

#define LOADC(arr, kq_) do { \
    _Pragma("unroll") \
    for (int s_ = 0; s_ < 5; ++s_) arr[s_] = ldB(Wh, wrow0, (kq_), s_, tid); \
} while (0)

#define STAGEC(arr, buf_) do { \
    _Pragma("unroll") \
    for (int s_ = 0; s_ < 5; ++s_) \
        *reinterpret_cast<uint2*>((buf_) + (s_ * 512 + tid) * 8) = arr[s_]; \
} while (0)

#define GEMM_STEP(kq_, buf_) do { \
    s16x8 a_ = *reinterpret_cast<const s16x8*>(sA + swzA(rw + l15, (kq_) * 64 + l4 * 16)); \
    _Pragma("unroll") \
    for (int f_ = 0; f_ < 10; ++f_) { \
        int col_ = cq + f_ * 16 + l15; \
        s16x8 b_ = *reinterpret_cast<const s16x8*>( \
            (buf_) + col_ * 64 + ((l4 ^ ((col_ >> 1) & 3)) << 4)); \
        acc[f_] = __builtin_amdgcn_mfma_f32_16x16x32_bf16(a_, b_, acc[f_], 0, 0, 0); \
    } \
} while (0)

// ---------------- edge GEMM + GATv2 scoring ----------------
// R8 structure; ONE change: xl/xr gathers issue before chunk-2's barrier so
// their HBM latency hides under GEMM2+GEMM3+spill (vmcnt never drained until
// scoring reads them). VGPR budget: ~100 + 40 AGPR, inside the <=128 bracket.
__global__ __launch_bounds__(512)
void k_edge(const float* __restrict__ eattr, const unsigned short* __restrict__ Wh,
            const unsigned short* __restrict__ y, const int* __restrict__ ei,
            const float* __restrict__ att, float* __restrict__ alphaE,
            float* __restrict__ denom)
{
    __shared__ unsigned char smem[57344];
    unsigned char* sA   = smem;
    unsigned char* buf0 = smem + 16384;
    unsigned char* buf1 = smem + 36864;
    unsigned char* sE   = smem + 15872;           // spill, after GEMM
    const int tid = threadIdx.x;
    const int e0 = blockIdx.x * 64;
    const int w = tid >> 6, l = tid & 63;
    const int rw = (w & 3) * 16;
    const int cq = (w >> 2) * 160;
    const int l15 = l & 15, l4 = l >> 4;
    const int wrow0 = 640;                        // We rows in Wh
    const unsigned int* y32 = reinterpret_cast<const unsigned int*>(y);

    uint2 bA[5], bB[5];
    LOADC(bA, 0);                                 // prefetch B chunk 0 first

    // edge endpoints (issued at entry)
    const int p = l >> 3, q = l & 7;
    const int e = e0 + w * 8 + p;
    const int src = ei[e];
    const int dst = ei[N_EDGES + e];

    // stage A (edge_attr fp32 -> bf16, nontemporal stream); E = 6250*64 exact
#pragma unroll
    for (int it = 0; it < 4; ++it) {
        int c = tid + it * 512;
        int row = c >> 5, qa = c & 31;
        f32x4 v = __builtin_nontemporal_load(
            reinterpret_cast<const f32x4*>(eattr + (size_t)(e0 + row) * 128 + qa * 4));
        uint2 pk = make_uint2(cvtpk(v[0], v[1]), cvtpk(v[2], v[3]));
        *reinterpret_cast<uint2*>(sA + swzA(row, qa * 8)) = pk;
    }

    f32x4 acc[10];
#pragma unroll
    for (int f = 0; f < 10; ++f) acc[f] = (f32x4){0.f, 0.f, 0.f, 0.f};

    uint4 xg[5], rg[5];

    LOADC(bB, 1); STAGEC(bA, buf0); bar_sync(); GEMM_STEP(0, buf0);
    LOADC(bA, 2); STAGEC(bB, buf1); bar_sync(); GEMM_STEP(1, buf1);
    LOADC(bB, 3); STAGEC(bA, buf0);
    // issue scoring gathers NOW: overlap GEMM2 + GEMM3 + spill (~3 barriers)
#pragma unroll
    for (int it = 0; it < 5; ++it) {
        int chk = it * 8 + q;
        xg[it] = *reinterpret_cast<const uint4*>(y32 + (size_t)src * 320 + chk * 4);
        rg[it] = *reinterpret_cast<const uint4*>(y32 + (size_t)dst * 320 + 160 + chk * 4);
    }
    bar_sync(); GEMM_STEP(2, buf0);
    STAGEC(bB, buf1); bar_sync(); GEMM_STEP(3, buf1);

    bar_sync();   // all MFMA LDS reads done -> safe to overwrite as sE

    // spill ea as paired-bf16 u32s, row stride 648B
#pragma unroll
    for (int fp = 0; fp < 5; ++fp) {
        int head = (cq >> 5) + fp;        // 0..9
#pragma unroll
        for (int j = 0; j < 4; ++j) {
            int row = rw + l4 * 4 + j;
            *reinterpret_cast<unsigned int*>(sE + row * 648 + (head * 16 + l15) * 4) =
                cvtpk(acc[2 * fp][j], acc[2 * fp + 1][j]);
        }
    }
    bar_sync();

    // ---- scoring: 64 lanes = 8 edges x 8 lanes, 5 iterations of 16B chunks ----
    float hv[5];
#pragma unroll
    for (int it = 0; it < 5; ++it) {
        int chk = it * 8 + q;             // chunk 0..39
        s16x8 ev = *reinterpret_cast<const s16x8*>(sE + (w * 8 + p) * 648 + chk * 16);
        int head = it * 2 + (q >> 2), c4 = q & 3;
        float4 alo = *reinterpret_cast<const float4*>(att + head * 32 + c4 * 4);
        float4 ahi = *reinterpret_cast<const float4*>(att + head * 32 + 16 + c4 * 4);
        const unsigned int* eu  = reinterpret_cast<const unsigned int*>(&ev);
        const unsigned int* xlu = reinterpret_cast<const unsigned int*>(&xg[it]);
        const unsigned int* xru = reinterpret_cast<const unsigned int*>(&rg[it]);
        const float* al = reinterpret_cast<const float*>(&alo);
        const float* ah = reinterpret_cast<const float*>(&ahi);
        float P1 = 0.f, P2 = 0.f;
#pragma unroll
        for (int i = 0; i < 4; ++i) {
            float mlo = lo16(eu[i]) + lo16(xlu[i]) + lo16(xru[i]);
            float mhi = hi16(eu[i]) + hi16(xlu[i]) + hi16(xru[i]);
            P1 = fmaf(al[i], mlo, P1);
            P2 = fmaf(al[i], fabsf(mlo), P2);
            P1 = fmaf(ah[i], mhi, P1);
            P2 = fmaf(ah[i], fabsf(mhi), P2);
        }
        // att.lrelu(m) = 0.6*att.m + 0.4*att.|m| (slope 0.2)
        float v = 0.6f * P1 + 0.4f * P2;
        v += __shfl_xor(v, 1);
        v += __shfl_xor(v, 2);
        hv[it] = v;                       // valid on lanes with (l&3)==0
    }
    if ((l & 3) == 0) {
        int par = (l >> 2) & 1;
#pragma unroll
        for (int it = 0; it < 5; ++it) {
            float ex = __expf(hv[it]);    // |logit| small: no max-shift needed
            int head = it * 2 + par;
            alphaE[(size_t)e * 10 + head] = ex;
            atomicAdd(&denom[(size_t)dst * 10 + head], ex);
        }
    }
}

// ---------------- aggregation (R6-exact version: plain loads, unroll 2) ------
__global__ __launch_bounds__(256)
void k_agg(const float* __restrict__ alphaE, const float* __restrict__ denom,
           const unsigned short* __restrict__ y, const int* __restrict__ ei,
           float* __restrict__ accC)
{
    const int lane = threadIdx.x & 63;
    const int hw = lane >> 5;             // which edge of the pair
    const int hl = lane & 31;
    const int wid = (blockIdx.x * blockDim.x + threadIdx.x) >> 6;
    const int nw = (gridDim.x * blockDim.x) >> 6;
    const unsigned int* y32 = reinterpret_cast<const unsigned int*>(y);
#pragma unroll 2
    for (int ep = wid; ep < N_EDGES / 2; ep += nw) {
        int e = ep * 2 + hw;
        int src = ei[e];
        int dst = ei[N_EDGES + e];
        float wv = 0.f;
        if (hl < 10)
            wv = alphaE[(size_t)e * 10 + hl] / (denom[(size_t)dst * 10 + hl] + 1e-16f);
        float sLO = 0.f, sHI = 0.f;
#pragma unroll
        for (int k = 0; k < 5; ++k) {
            int g = k * 32 + hl;          // u32 index in xl block (0..159)
            float wh = __shfl(wv, (hw << 5) | (k * 2 + (hl >> 4)));
            unsigned int u = y32[(size_t)src * 320 + g];
            sLO = fmaf(wh, lo16(u), sLO);
            sHI = fmaf(wh, hi16(u), sHI);
        }
        sLO += __shfl_xor(sLO, 16);
        sHI += __shfl_xor(sHI, 16);
        atomicAdd(&accC[(size_t)dst * 32 + hl], (hl & 16) ? sHI : sLO);
    }
}

// ---------------- per-node finish + per-graph mean pool ----------------
__global__ __launch_bounds__(256)
void k_pool(const float* __restrict__ accC, const float* __restrict__ bias_out,
            const int* __restrict__ batch, float* __restrict__ pooled,
            float* __restrict__ cnt)
{
    __shared__ float sm[G * C];
    __shared__ float smc[G];
    int tid = threadIdx.x;
    for (int i = tid; i < G * C; i += 256) sm[i] = 0.f;
    if (tid < G) smc[tid] = 0.f;
    __syncthreads();
    int base = blockIdx.x * 2048;
    for (int it = 0; it < 8; ++it) {
        int idx = base + it * 256 + tid;
        if (idx < N_NODES * C) {
            int n = idx >> 5, c = idx & 31;
            float v = __builtin_nontemporal_load(accC + idx) * 0.1f + bias_out[c];
            v = fmaxf(v, 0.f);
            int gr = batch[n];
            atomicAdd(&sm[gr * C + c], v);
            if (c == 0) atomicAdd(&smc[gr], 1.f);
        }
    }
    __syncthreads();
    for (int i = tid; i < G * C; i += 256)
        if (sm[i] != 0.f) atomicAdd(&pooled[i], sm[i]);
    if (tid < G && smc[tid] != 0.f) atomicAdd(&cnt[tid], smc[tid]);
}

// ---------------- final tiny classifier ----------------
__global__ void k_final(const float* __restrict__ pooled, const float* __restrict__ cnt,
                        const float* __restrict__ Wlin, const float* __restrict__ blin,
                        float* __restrict__ out)
{
    int g = threadIdx.x;
    if (g >= G) return;
    float cg = fmaxf(cnt[g], 1.f);
    float s0 = blin[0], s1 = blin[1];
#pragma unroll
    for (int c = 0; c < C; ++c) {
        float p = pooled[g * C + c] / cg;
        s0 += p * Wlin[c];
        s1 += p * Wlin[C + c];
    }
    out[g * 2 + 0] = s0;
    out[g * 2 + 1] = s1;
}

extern "C" void kernel_launch(void* const* d_in, const int* in_sizes, int n_in,
                              void* d_out, int out_size, void* d_ws, size_t ws_size,
                              hipStream_t stream)
{
    const float* x         = (const float*)d_in[0];
    const float* edge_attr = (const float*)d_in[1];
    const float* bn_gamma  = (const float*)d_in[2];
    const float* bn_beta   = (const float*)d_in[3];
    const float* bn_mean   = (const float*)d_in[4];
    const float* bn_var    = (const float*)d_in[5];
    const float* Wl        = (const float*)d_in[6];
    const float* bl        = (const float*)d_in[7];
    const float* Wr        = (const float*)d_in[8];
    const float* br        = (const float*)d_in[9];
    const float* We        = (const float*)d_in[10];
    const float* att       = (const float*)d_in[11];
    const float* bias_out  = (const float*)d_in[12];
    const float* Wlin      = (const float*)d_in[13];
    const float* blin      = (const float*)d_in[14];
    const int* edge_index  = (const int*)d_in[15];
    const int* batch       = (const int*)d_in[16];
    float* out = (float*)d_out;

    char* ws = (char*)d_ws;
    unsigned short* Wh    = (unsigned short*)(ws + OFF_WH);
    float* scale          = (float*)(ws + OFF_SCALE);
    float* shift          = (float*)(ws + OFF_SHIFT);
    unsigned short* y     = (unsigned short*)(ws + OFF_Y);
    float* alphaE         = (float*)(ws + OFF_ALPHA);
    float* denom          = (float*)(ws + OFF_DENOM);
    float* accC           = (float*)(ws + OFF_ACC);
    float* pooled         = (float*)(ws + OFF_POOL);
    float* cnt            = (float*)(ws + OFF_CNT);

    k_init<<<1024, 256, 0, stream>>>(Wl, Wr, We, bn_gamma, bn_beta, bn_mean, bn_var,
                                     Wh, scale, shift, denom, accC, pooled, cnt);
    k_node_gemm<<<dim3(782, 2), 512, 0, stream>>>(x, Wh, scale, shift, bl, br, y);
    k_edge<<<6250, 512, 0, stream>>>(edge_attr, Wh, y, edge_index, att, alphaE, denom);
    k_agg<<<2048, 256, 0, stream>>>(alphaE, denom, y, edge_index, accC);
    k_pool<<<782, 256, 0, stream>>>(accC, bias_out, batch, pooled, cnt);
    k_final<<<1, 64, 0, stream>>>(pooled, cnt, Wlin, blin, out);
}